// Round 2
// baseline (232.539 us; speedup 1.0000x reference)
//
#include <hip/hip_runtime.h>
#include <math.h>

// Problem constants
#define Bn   4
#define Cc   64
#define Hh   128
#define Ww   128
#define Oo   64
#define HW   16384
#define CIN  128
#define KK   9
#define NPAR 27

// Workspace layout (float offsets)
#define WB2_OFF 0        // bf16 W2[32][1152] = 36864 shorts = 18432 float slots
#define WB_OFF  18432    // bf16 W [64][576]  = 36864 shorts = 18432 float slots
#define PAR_OFF 36864    // f32 par[B][27][HW]

typedef __attribute__((ext_vector_type(8))) short bf16x8;
typedef __attribute__((ext_vector_type(4))) float f32x4;
typedef __attribute__((ext_vector_type(2), aligned(4))) float f32x2u;  // 4B-aligned pair

__device__ __forceinline__ short f2bf(float f) {
    unsigned u = __builtin_bit_cast(unsigned, f);
    u += 0x7FFFu + ((u >> 16) & 1u);        // RNE
    return (short)(u >> 16);
}

// ---------------------------------------------------------------------------
// Prepass: bf16 weight copies. Flat layouts line up:
//   wb2[j][c*9+k]: rows 0-17 = w_off flat, 18-26 = w_mod flat, 27-31 = 0
//   wb [o][c*9+k]: = w_reg flat
// ---------------------------------------------------------------------------
__global__ void prep_weights(const float* __restrict__ w_off,
                             const float* __restrict__ w_mod,
                             const float* __restrict__ w_reg,
                             float* __restrict__ ws) {
    int i = blockIdx.x * 256 + threadIdx.x;
    short* wb2 = (short*)(ws + WB2_OFF);
    short* wb  = (short*)(ws + WB_OFF);
    if (i < 32 * 1152) {
        int j = i / 1152;
        float v = 0.f;
        if (j < 18)      v = w_off[i];
        else if (j < 27) v = w_mod[i - 18 * 1152];
        wb2[i] = f2bf(v);
    }
    if (i < 64 * 576) wb[i] = f2bf(w_reg[i]);
}

// ---------------------------------------------------------------------------
// conv_mfma: 3x3 conv 128->27(pad 32) via MFMA per 16x4-pixel tile.
// C[32][64] = W2[32][1152] x V[1152][64], K chunked 18x64.
// Round-2 restructure: back to 4 waves/256 thr (round-1's 8-wave TLP bump
// REGRESSED 78->88us; VGPR=32 showed the gather was load-serialized).
// launch_bounds(256,4) -> 128-VGPR budget; gather split into issue-phase
// (all 16 loads batched into a register array, ILP) + consume-phase
// (select+f2bf), with chunk cc+1's loads issued BEFORE the MFMA phase of
// chunk cc so they fly across barrier+MFMA (T14 async-stage split).
// ---------------------------------------------------------------------------
#define VSTR 72   // V_T row stride in bf16 (64 + 8 pad -> 2-way banks, free)

__global__ __launch_bounds__(256, 4)
void conv_mfma(const float* __restrict__ x, const float* __restrict__ g,
               const float* __restrict__ ws_,
               const float* __restrict__ b_off, const float* __restrict__ b_mod,
               float* __restrict__ parw) {
    __shared__ __align__(16) short V[64 * VSTR];

    const int tid = threadIdx.x;
    const int l = tid & 63, lm = l & 15, quad = l >> 4;
    const int w = __builtin_amdgcn_readfirstlane(tid >> 6);   // wave = n-tile
    const int b = blockIdx.z;
    const int ho0 = blockIdx.y * 4, wo0 = blockIdx.x * 16;
    const int ho_l = ho0 + (l >> 4), wo_l = wo0 + lm;         // staging pixel l

    const short* wb2 = (const short*)(ws_ + WB2_OFF);

    f32x4 acc0 = {0.f, 0.f, 0.f, 0.f}, acc1 = {0.f, 0.f, 0.f, 0.f};

    float    val[16];
    unsigned okm;

    auto ISSUE = [&](int cc) {
        okm = 0u;
#pragma unroll
        for (int i = 0; i < 16; i++) {
            int kkg = cc * 64 + w * 16 + i;       // wave-uniform
            int c = (kkg * 7282) >> 16;           // kkg/9 exact for <5832
            int k = kkg - c * 9;
            int dy = k / 3, dx = k - dy * 3;
            const float* plane = (c < Cc) ? (x + ((size_t)(b * Cc + c) << 14))
                                          : (g + ((size_t)(b * Cc + c - Cc) << 14));
            int y = ho_l + dy - 1, xx = wo_l + dx - 1;
            bool ok = ((unsigned)y < 128u) && ((unsigned)xx < 128u);
            int cy = min(max(y, 0), 127), cx = min(max(xx, 0), 127);
            val[i] = plane[(cy << 7) + cx];
            okm |= (ok ? 1u : 0u) << i;
        }
    };

    ISSUE(0);                                     // prologue prefetch

    for (int cc = 0; cc < 18; cc++) {
        // consume chunk cc (loads issued last iteration / prologue)
        union { short s[16]; bf16x8 v[2]; } u;
#pragma unroll
        for (int i = 0; i < 16; i++)
            u.s[i] = f2bf(((okm >> i) & 1u) ? val[i] : 0.f);

        __syncthreads();                          // prev MFMA reads of V done
        {
            bf16x8* dst = (bf16x8*)&V[l * VSTR + w * 16];
            dst[0] = u.v[0];
            dst[1] = u.v[1];
        }
        if (cc < 17) ISSUE(cc + 1);               // prefetch across barrier+MFMA
        __syncthreads();                          // V ready
#pragma unroll
        for (int ks = 0; ks < 2; ks++) {
            bf16x8 bfr = *(const bf16x8*)&V[(w * 16 + lm) * VSTR + ks * 32 + quad * 8];
            bf16x8 a0 = *(const bf16x8*)(wb2 + lm * 1152 + cc * 64 + ks * 32 + quad * 8);
            bf16x8 a1 = *(const bf16x8*)(wb2 + (16 + lm) * 1152 + cc * 64 + ks * 32 + quad * 8);
            acc0 = __builtin_amdgcn_mfma_f32_16x16x32_bf16(a0, bfr, acc0, 0, 0, 0);
            acc1 = __builtin_amdgcn_mfma_f32_16x16x32_bf16(a1, bfr, acc1, 0, 0, 0);
        }
    }

    // Epilogue: D[row j][col lm] -> par channels, fused bias/coords/sigmoid
    const int ho = ho0 + w, wo = wo0 + lm;
    const int pix = (ho << 7) + wo;
    float* par = parw + (size_t)b * NPAR * HW + pix;
#pragma unroll
    for (int mt = 0; mt < 2; mt++) {
        f32x4 a = mt ? acc1 : acc0;
#pragma unroll
        for (int reg = 0; reg < 4; reg++) {
            int j = mt * 16 + quad * 4 + reg;
            float v = a[reg];
            if (j < 18) {
                int k = j >> 1;
                float vb = v + b_off[j];
                if (j & 1) par[(size_t)(9 + k) * HW] = vb + (float)(k - (k / 3) * 3 + wo - 1);
                else       par[(size_t)k * HW]       = vb + (float)(k / 3 + ho - 1);
            } else if (j < 27) {
                int k = j - 18;
                par[(size_t)(18 + k) * HW] = 2.f / (1.f + __expf(-(v + b_mod[k])));
            }
        }
    }
}

// ---------------------------------------------------------------------------
// deform_mfma: C[64o][64px] = W[64][576] x V[576][64] per 16x4-px tile.
// Stage A: bilinear params; x-corner pairs folded into pre-transformed
// weights so phase 1 is 2 dwordx2 loads + 4 FMA per element.
// Round-2: 4 waves/256 thr, launch_bounds(256,4) for a 128-VGPR budget.
// Gather issue-phase batches all 32 dwordx2 loads of the chunk into
// register arrays p0/p1 (64 VGPR) -- round 0/1's VGPR=32/36 serialized
// these into load->vmcnt(0)->use chains (the real latency bottleneck:
// MfmaUtil 2%, VALUBusy 22%, HBM 9%, yet 88us). Chunk ch+1's loads are
// issued before chunk ch's MFMA phase (prefetch spans barrier+MFMA).
// sWt is re-read from LDS at consume time to keep VGPR under budget.
// ---------------------------------------------------------------------------
__global__ __launch_bounds__(256, 4)
void deform_mfma(const float* __restrict__ x, const float* __restrict__ ws_,
                 const float* __restrict__ par_base, float* __restrict__ out) {
    __shared__ int2   sIdx[576];
    __shared__ float4 sWt [576];
    __shared__ __align__(16) short V[64 * VSTR];

    const int tid = threadIdx.x;
    const int l = tid & 63;
    const int lm = l & 15, quad = l >> 4;
    const int w = __builtin_amdgcn_readfirstlane(tid >> 6);   // wave = o-tile
    const int b = blockIdx.z;

    const float* par = par_base + (size_t)b * NPAR * HW;
    const short* wb  = (const short*)(ws_ + WB_OFF);
    const float* xb  = x + ((size_t)(b * Cc) << 14);

    // Stage A: bilinear params for 9 taps x 64 pixels
    for (int s = tid; s < 576; s += 256) {
        int k = s >> 6;
        int sl = s & 63;
        int sho = blockIdx.y * 4 + (sl >> 4);
        int swo = blockIdx.x * 16 + (sl & 15);
        int spix = (sho << 7) + swo;
        float py = par[(size_t)k * HW + spix];
        float px = par[(size_t)(9 + k) * HW + spix];
        float m  = par[(size_t)(18 + k) * HW + spix];
        float fy = floorf(py), fx = floorf(px);
        int y0 = (int)fy, x0 = (int)fx;
        int y1 = y0 + 1;
        float wy1 = py - fy, wx1 = px - fx;
        float wy0 = 1.f - wy1, wx0 = 1.f - wx1;
        bool vy0 = (unsigned)y0 < 128u, vy1 = (unsigned)y1 < 128u;
        bool vx0 = (unsigned)x0 < 128u, vx1 = (unsigned)(x0 + 1) < 128u;
        int cy0 = min(max(y0, 0), 127), cy1 = min(max(y1, 0), 127);
        int bx2 = min(max(x0, 0), 126);
        bool sel_lo = (x0 < 0), sel_hi = (x0 > 126);
        float w00 = (vy0 && vx0) ? wy0 * wx0 * m : 0.f;
        float w01 = (vy0 && vx1) ? wy0 * wx1 * m : 0.f;
        float w10 = (vy1 && vx0) ? wy1 * wx0 * m : 0.f;
        float w11 = (vy1 && vx1) ? wy1 * wx1 * m : 0.f;
        // fold boundary handling into pair weights: wa->[bx2], wb->[bx2+1]
        float wa0 = sel_lo ? w01 : (sel_hi ? 0.f : w00);
        float wb0 = sel_hi ? w00 : (sel_lo ? 0.f : w01);
        float wa1 = sel_lo ? w11 : (sel_hi ? 0.f : w10);
        float wb1 = sel_hi ? w10 : (sel_lo ? 0.f : w11);
        sIdx[s] = make_int2((cy0 << 7) + bx2, (cy1 << 7) + bx2);
        sWt[s]  = make_float4(wa0, wb0, wa1, wb1);
    }

    f32x4 acc[4];
#pragma unroll
    for (int nb = 0; nb < 4; nb++) acc[nb] = (f32x4){0.f, 0.f, 0.f, 0.f};

    const int wrow = w * 16 + lm;     // this wave's A row for lane

    f32x2u p0[16], p1[16];

    auto ISSUE = [&](int ch) {
#pragma unroll
        for (int i = 0; i < 16; i++) {
            int kkg = ch * 64 + w * 16 + i;            // wave-uniform
            int c = (kkg * 7282) >> 16;                // kkg/9
            int k = kkg - c * 9;
            int2 id = sIdx[(k << 6) + l];
            const float* xq = xb + ((size_t)c << 14);  // scalar base
            p0[i] = *(const f32x2u*)(xq + id.x);
            p1[i] = *(const f32x2u*)(xq + id.y);
        }
    };

    __syncthreads();                  // sIdx/sWt ready
    ISSUE(0);                         // prologue prefetch

    for (int ch = 0; ch < 9; ch++) {
        // consume chunk ch
        union { short s[16]; bf16x8 v[2]; } u;
#pragma unroll
        for (int i = 0; i < 16; i++) {
            int kkg = ch * 64 + w * 16 + i;
            int c = (kkg * 7282) >> 16;
            int k = kkg - c * 9;
            float4 wv = sWt[(k << 6) + l];
            u.s[i] = f2bf(wv.x * p0[i].x + wv.y * p0[i].y + wv.z * p1[i].x + wv.w * p1[i].y);
        }

        __syncthreads();              // prev MFMA reads of V done
        {
            bf16x8* dst = (bf16x8*)&V[l * VSTR + w * 16];
            dst[0] = u.v[0];
            dst[1] = u.v[1];
        }
        if (ch < 8) ISSUE(ch + 1);    // prefetch across barrier+MFMA
        __syncthreads();              // V ready
#pragma unroll
        for (int ks = 0; ks < 2; ks++) {
            bf16x8 a = *(const bf16x8*)(wb + wrow * 576 + ch * 64 + ks * 32 + quad * 8);
#pragma unroll
            for (int nb = 0; nb < 4; nb++) {
                bf16x8 bf = *(const bf16x8*)&V[(nb * 16 + lm) * VSTR + ks * 32 + quad * 8];
                acc[nb] = __builtin_amdgcn_mfma_f32_16x16x32_bf16(a, bf, acc[nb], 0, 0, 0);
            }
        }
    }

    const int wo = blockIdx.x * 16 + lm;
#pragma unroll
    for (int nb = 0; nb < 4; nb++) {
        int ho = blockIdx.y * 4 + nb;
        float* op = out + ((size_t)(b * Oo + w * 16 + quad * 4) << 14) + (ho << 7) + wo;
#pragma unroll
        for (int reg = 0; reg < 4; reg++)
            op[(size_t)reg << 14] = acc[nb][reg];
    }
}

// ---------------------------------------------------------------------------
extern "C" void kernel_launch(void* const* d_in, const int* in_sizes, int n_in,
                              void* d_out, int out_size, void* d_ws, size_t ws_size,
                              hipStream_t stream) {
    const float* x     = (const float*)d_in[0];
    const float* guide = (const float*)d_in[1];
    const float* w_off = (const float*)d_in[2];
    const float* b_off = (const float*)d_in[3];
    const float* w_mod = (const float*)d_in[4];
    const float* b_mod = (const float*)d_in[5];
    const float* w_reg = (const float*)d_in[6];
    float* out = (float*)d_out;
    float* ws  = (float*)d_ws;

    hipLaunchKernelGGL(prep_weights, dim3((32 * 1152 + 255) / 256), dim3(256),
                       0, stream, w_off, w_mod, w_reg, ws);
    hipLaunchKernelGGL(conv_mfma, dim3(Ww / 16, Hh / 4, Bn), dim3(256),
                       0, stream, x, guide, ws, b_off, b_mod, ws + PAR_OFF);
    hipLaunchKernelGGL(deform_mfma, dim3(Ww / 16, Hh / 4, Bn), dim3(256),
                       0, stream, x, ws, ws + PAR_OFF, out);
}

// Round 3
// 231.565 us; speedup vs baseline: 1.0042x; 1.0042x over previous
//
#include <hip/hip_runtime.h>
#include <math.h>

// Problem constants
#define Bn   4
#define Cc   64
#define Hh   128
#define Ww   128
#define Oo   64
#define HW   16384
#define CIN  128
#define KK   9
#define NPAR 27

// Workspace layout (float offsets)
#define WB2_OFF 0        // bf16 W2[32][1152] = 36864 shorts = 18432 float slots
#define WB_OFF  18432    // bf16 W [64][576]  = 36864 shorts = 18432 float slots
#define PAR_OFF 36864    // f32 par[B][27][HW]

typedef __attribute__((ext_vector_type(8))) short bf16x8;
typedef __attribute__((ext_vector_type(4))) float f32x4;
typedef __attribute__((ext_vector_type(2), aligned(4))) float f32x2u;  // 4B-aligned pair

__device__ __forceinline__ short f2bf(float f) {
    unsigned u = __builtin_bit_cast(unsigned, f);
    u += 0x7FFFu + ((u >> 16) & 1u);        // RNE
    return (short)(u >> 16);
}

// ---------------------------------------------------------------------------
// Prepass: bf16 weight copies (unchanged).
// ---------------------------------------------------------------------------
__global__ void prep_weights(const float* __restrict__ w_off,
                             const float* __restrict__ w_mod,
                             const float* __restrict__ w_reg,
                             float* __restrict__ ws) {
    int i = blockIdx.x * 256 + threadIdx.x;
    short* wb2 = (short*)(ws + WB2_OFF);
    short* wb  = (short*)(ws + WB_OFF);
    if (i < 32 * 1152) {
        int j = i / 1152;
        float v = 0.f;
        if (j < 18)      v = w_off[i];
        else if (j < 27) v = w_mod[i - 18 * 1152];
        wb2[i] = f2bf(v);
    }
    if (i < 64 * 576) wb[i] = f2bf(w_reg[i]);
}

// ---------------------------------------------------------------------------
// conv_mfma round 3: LDS-tiled. Rounds 0-2 all stalled at 78-88us with
// MfmaUtil~2/VALUBusy~23/HBM~8%: VMEM-issue-bound (288 divergent loads/wave,
// ~16cyc TA each). Fix = reuse: stage the 6x24 window for 64 channels f32
// in LDS ONCE (coalesced dwordx4, 9 instrs/thread), gather the 3x3 window
// from LDS instead. x staged for chunks 0-8, guide re-staged for 9-17
// (kkg<576 <=> c<64, boundary clean). f32 tile => numerics identical.
// ---------------------------------------------------------------------------
#define VSTR 72   // V row stride in bf16 (64 + 8 pad)
#define CTR  6    // conv tile rows
#define CTC  24   // conv tile cols (4-aligned base => 16B-aligned dwordx4)

__global__ __launch_bounds__(256, 4)
void conv_mfma(const float* __restrict__ x, const float* __restrict__ g,
               const float* __restrict__ ws_,
               const float* __restrict__ b_off, const float* __restrict__ b_mod,
               float* __restrict__ parw) {
    __shared__ float xt[64 * CTR * CTC];            // 36864 B
    __shared__ __align__(16) short V[64 * VSTR];    // 9216 B

    const int tid = threadIdx.x;
    const int l = tid & 63, lm = l & 15, quad = l >> 4;
    const int w = __builtin_amdgcn_readfirstlane(tid >> 6);   // wave = n-tile
    const int b = blockIdx.z;
    const int ho0 = blockIdx.y * 4, wo0 = blockIdx.x * 16;
    const int ho_l = ho0 + (l >> 4), wo_l = wo0 + lm;         // gather pixel l

    const int row_base = min(max(ho0 - 1, 0), 128 - CTR);
    const int col_base = min(max(wo0 - 4, 0), 128 - CTC);     // 4-aligned

    const short* wb2 = (const short*)(ws_ + WB2_OFF);

    // stage x tile: 64c x 6r x 24cols, 2304 dwordx4 / 256 thr = 9 each
    const float* xb = x + ((size_t)(b * Cc) << 14);
    const float* gb = g + ((size_t)(b * Cc) << 14);
    for (int s = tid; s < 64 * CTR * 6; s += 256) {
        int c = s / 36, rem = s - c * 36, r = rem / 6, e = rem - r * 6;
        *(f32x4*)&xt[(c * CTR + r) * CTC + e * 4] =
            *(const f32x4*)(xb + ((size_t)c << 14) + ((row_base + r) << 7) + col_base + e * 4);
    }
    __syncthreads();

    f32x4 acc0 = {0.f, 0.f, 0.f, 0.f}, acc1 = {0.f, 0.f, 0.f, 0.f};

    for (int cc = 0; cc < 18; cc++) {
        if (cc == 9) {                              // re-stage: guide channels
            __syncthreads();                        // all tile reads of x done
            for (int s = tid; s < 64 * CTR * 6; s += 256) {
                int c = s / 36, rem = s - c * 36, r = rem / 6, e = rem - r * 6;
                *(f32x4*)&xt[(c * CTR + r) * CTC + e * 4] =
                    *(const f32x4*)(gb + ((size_t)c << 14) + ((row_base + r) << 7) + col_base + e * 4);
            }
            __syncthreads();
        }
        union { short s[16]; bf16x8 v[2]; } u;
#pragma unroll
        for (int i = 0; i < 16; i++) {
            int kkg = cc * 64 + w * 16 + i;       // wave-uniform -> SALU
            int c = (kkg * 7282) >> 16;           // kkg/9 exact for <5832
            int k = kkg - c * 9;
            int dy = k / 3, dx = k - dy * 3;
            int ct = c & 63;
            int y = ho_l + dy - 1, xx = wo_l + dx - 1;
            bool ok = ((unsigned)y < 128u) && ((unsigned)xx < 128u);
            int idx = ok ? ((ct * CTR + (y - row_base)) * CTC + (xx - col_base)) : 0;
            float val = xt[idx];
            u.s[i] = f2bf(ok ? val : 0.f);
        }
        __syncthreads();                          // prev MFMA reads of V done
        {
            bf16x8* dst = (bf16x8*)&V[l * VSTR + w * 16];
            dst[0] = u.v[0];
            dst[1] = u.v[1];
        }
        __syncthreads();                          // V ready
#pragma unroll
        for (int ks = 0; ks < 2; ks++) {
            bf16x8 bfr = *(const bf16x8*)&V[(w * 16 + lm) * VSTR + ks * 32 + quad * 8];
            bf16x8 a0 = *(const bf16x8*)(wb2 + lm * 1152 + cc * 64 + ks * 32 + quad * 8);
            bf16x8 a1 = *(const bf16x8*)(wb2 + (16 + lm) * 1152 + cc * 64 + ks * 32 + quad * 8);
            acc0 = __builtin_amdgcn_mfma_f32_16x16x32_bf16(a0, bfr, acc0, 0, 0, 0);
            acc1 = __builtin_amdgcn_mfma_f32_16x16x32_bf16(a1, bfr, acc1, 0, 0, 0);
        }
    }

    // Epilogue: D[row j][col lm] -> par channels, fused bias/coords/sigmoid
    const int ho = ho0 + w, wo = wo0 + lm;
    const int pix = (ho << 7) + wo;
    float* par = parw + (size_t)b * NPAR * HW + pix;
#pragma unroll
    for (int mt = 0; mt < 2; mt++) {
        f32x4 a = mt ? acc1 : acc0;
#pragma unroll
        for (int reg = 0; reg < 4; reg++) {
            int j = mt * 16 + quad * 4 + reg;
            float v = a[reg];
            if (j < 18) {
                int k = j >> 1;
                float vb = v + b_off[j];
                if (j & 1) par[(size_t)(9 + k) * HW] = vb + (float)(k - (k / 3) * 3 + wo - 1);
                else       par[(size_t)k * HW]       = vb + (float)(k / 3 + ho - 1);
            } else if (j < 27) {
                int k = j - 18;
                par[(size_t)(18 + k) * HW] = 2.f / (1.f + __expf(-(v + b_mod[k])));
            }
        }
    }
}

// ---------------------------------------------------------------------------
// deform_mfma round 3: LDS-tiled bilinear gather. Tile = 32ch x 10r x 24c
// f32 (halo +-2 around the 16x4 px window), staged per c-half; K rechunked
// 18 x 32 so the half boundary is clean (288 = 9*32, c = kkg/9 < 32 <=>
// kkg < 288). Gather = 2 x ds_read2_b32 pairs per sample from LDS instead
// of 2 divergent global dwordx2 (the round-0/1/2 bottleneck). Stage A
// additionally checks every sample's clamped corners lie in the tile;
// if not (offset beyond halo: ~5 samples expected in the whole tensor at
// sigma~0.35) the block takes the old global-gather path (block-uniform).
// f32 corners => numerics identical to previous rounds.
// ---------------------------------------------------------------------------
#define TRr   10
#define TCc   24
#define VSTR2 40  // V row stride in bf16 (32 + 8 pad)

__global__ __launch_bounds__(256, 4)
void deform_mfma(const float* __restrict__ x, const float* __restrict__ ws_,
                 const float* __restrict__ par_base, float* __restrict__ out) {
    __shared__ float xt[32 * TRr * TCc];            // 30720 B
    __shared__ __align__(16) short V[64 * VSTR2];   // 5120 B
    __shared__ int2   sIdx[576];                    // image-coord pair bases
    __shared__ float4 sWt [576];
    __shared__ int sOk;

    const int tid = threadIdx.x;
    const int l = tid & 63;
    const int lm = l & 15, quad = l >> 4;
    const int w = __builtin_amdgcn_readfirstlane(tid >> 6);   // wave = o-tile
    const int b = blockIdx.z;

    const int ho0 = blockIdx.y * 4, wo0 = blockIdx.x * 16;
    const int row_base = min(max(ho0 - 3, 0), 128 - TRr);
    const int col_base = min(max(wo0 - 4, 0), 128 - TCc);     // 4-aligned

    const float* par = par_base + (size_t)b * NPAR * HW;
    const short* wb  = (const short*)(ws_ + WB_OFF);
    const float* xb  = x + ((size_t)(b * Cc) << 14);

    if (tid == 0) sOk = 1;
    __syncthreads();

    // Stage A: bilinear params for 9 taps x 64 pixels + in-tile check
    int okAll = 1;
    for (int s = tid; s < 576; s += 256) {
        int k = s >> 6;
        int sl = s & 63;
        int sho = ho0 + (sl >> 4);
        int swo = wo0 + (sl & 15);
        int spix = (sho << 7) + swo;
        float py = par[(size_t)k * HW + spix];
        float px = par[(size_t)(9 + k) * HW + spix];
        float m  = par[(size_t)(18 + k) * HW + spix];
        float fy = floorf(py), fx = floorf(px);
        int y0 = (int)fy, x0 = (int)fx;
        int y1 = y0 + 1;
        float wy1 = py - fy, wx1 = px - fx;
        float wy0 = 1.f - wy1, wx0 = 1.f - wx1;
        bool vy0 = (unsigned)y0 < 128u, vy1 = (unsigned)y1 < 128u;
        bool vx0 = (unsigned)x0 < 128u, vx1 = (unsigned)(x0 + 1) < 128u;
        int cy0 = min(max(y0, 0), 127), cy1 = min(max(y1, 0), 127);
        int bx2 = min(max(x0, 0), 126);
        bool sel_lo = (x0 < 0), sel_hi = (x0 > 126);
        float w00 = (vy0 && vx0) ? wy0 * wx0 * m : 0.f;
        float w01 = (vy0 && vx1) ? wy0 * wx1 * m : 0.f;
        float w10 = (vy1 && vx0) ? wy1 * wx0 * m : 0.f;
        float w11 = (vy1 && vx1) ? wy1 * wx1 * m : 0.f;
        // fold boundary handling into pair weights: wa->[bx2], wb->[bx2+1]
        float wa0 = sel_lo ? w01 : (sel_hi ? 0.f : w00);
        float wb0 = sel_hi ? w00 : (sel_lo ? 0.f : w01);
        float wa1 = sel_lo ? w11 : (sel_hi ? 0.f : w10);
        float wb1 = sel_hi ? w10 : (sel_lo ? 0.f : w11);
        sIdx[s] = make_int2((cy0 << 7) + bx2, (cy1 << 7) + bx2);
        sWt[s]  = make_float4(wa0, wb0, wa1, wb1);
        bool in = ((unsigned)(cy0 - row_base) <= (unsigned)(TRr - 1)) &&
                  ((unsigned)(cy1 - row_base) <= (unsigned)(TRr - 1)) &&
                  ((unsigned)(bx2 - col_base) <= (unsigned)(TCc - 2));
        if (!in) okAll = 0;
    }
    if (!okAll) sOk = 0;

    // stage tile for c-half 0 (wasted only if slow path triggers; rare)
    for (int s = tid; s < 32 * TRr * 6; s += 256) {
        int c = s / 60, rem = s - c * 60, r = rem / 6, e = rem - r * 6;
        *(f32x4*)&xt[(c * TRr + r) * TCc + e * 4] =
            *(const f32x4*)(xb + ((size_t)c << 14) + ((row_base + r) << 7) + col_base + e * 4);
    }
    __syncthreads();
    const int fast = sOk;                 // block-uniform

    f32x4 acc[4];
#pragma unroll
    for (int nb = 0; nb < 4; nb++) acc[nb] = (f32x4){0.f, 0.f, 0.f, 0.f};

    const int wrow = w * 16 + lm;         // this wave's A row for lane

    for (int ch = 0; ch < 18; ch++) {     // 18 chunks of K=32
        if (ch == 9 && fast) {            // re-stage: c-half 1
            // all half-0 tile reads finished (chunk-8's barriers passed)
            for (int s = tid; s < 32 * TRr * 6; s += 256) {
                int c = s / 60, rem = s - c * 60, r = rem / 6, e = rem - r * 6;
                *(f32x4*)&xt[(c * TRr + r) * TCc + e * 4] =
                    *(const f32x4*)(xb + ((size_t)(32 + c) << 14) + ((row_base + r) << 7) + col_base + e * 4);
            }
            __syncthreads();
        }
        union { short s[8]; bf16x8 v; } u;
        if (fast) {
#pragma unroll
            for (int i = 0; i < 8; i++) {
                int kkg = ch * 32 + w * 8 + i;             // wave-uniform -> SALU
                int c = (kkg * 7282) >> 16;                // kkg/9
                int k = kkg - c * 9;
                int ct = c & 31;
                int2   id = sIdx[(k << 6) + l];
                float4 wv = sWt [(k << 6) + l];
                int ty0 = (id.x >> 7) - row_base;
                int ty1 = (id.y >> 7) - row_base;
                int tx  = (id.x & 127) - col_base;
                const float* tb = &xt[ct * (TRr * TCc)];
                f32x2u p0 = *(const f32x2u*)&tb[ty0 * TCc + tx];
                f32x2u p1 = *(const f32x2u*)&tb[ty1 * TCc + tx];
                u.s[i] = f2bf(wv.x * p0.x + wv.y * p0.y + wv.z * p1.x + wv.w * p1.y);
            }
        } else {
#pragma unroll
            for (int i = 0; i < 8; i++) {
                int kkg = ch * 32 + w * 8 + i;
                int c = (kkg * 7282) >> 16;
                int k = kkg - c * 9;
                int2   id = sIdx[(k << 6) + l];
                float4 wv = sWt [(k << 6) + l];
                const float* xq = xb + ((size_t)c << 14);
                f32x2u p0 = *(const f32x2u*)(xq + id.x);
                f32x2u p1 = *(const f32x2u*)(xq + id.y);
                u.s[i] = f2bf(wv.x * p0.x + wv.y * p0.y + wv.z * p1.x + wv.w * p1.y);
            }
        }
        __syncthreads();                  // prev MFMA reads of V done
        *(bf16x8*)&V[l * VSTR2 + w * 8] = u.v;
        __syncthreads();                  // V ready
        bf16x8 a = *(const bf16x8*)(wb + wrow * 576 + ch * 32 + quad * 8);
#pragma unroll
        for (int nb = 0; nb < 4; nb++) {
            bf16x8 bf = *(const bf16x8*)&V[(nb * 16 + lm) * VSTR2 + quad * 8];
            acc[nb] = __builtin_amdgcn_mfma_f32_16x16x32_bf16(a, bf, acc[nb], 0, 0, 0);
        }
    }

    const int wo = blockIdx.x * 16 + lm;
#pragma unroll
    for (int nb = 0; nb < 4; nb++) {
        int ho = blockIdx.y * 4 + nb;
        float* op = out + ((size_t)(b * Oo + w * 16 + quad * 4) << 14) + (ho << 7) + wo;
#pragma unroll
        for (int reg = 0; reg < 4; reg++)
            op[(size_t)reg << 14] = acc[nb][reg];
    }
}

// ---------------------------------------------------------------------------
extern "C" void kernel_launch(void* const* d_in, const int* in_sizes, int n_in,
                              void* d_out, int out_size, void* d_ws, size_t ws_size,
                              hipStream_t stream) {
    const float* x     = (const float*)d_in[0];
    const float* guide = (const float*)d_in[1];
    const float* w_off = (const float*)d_in[2];
    const float* b_off = (const float*)d_in[3];
    const float* w_mod = (const float*)d_in[4];
    const float* b_mod = (const float*)d_in[5];
    const float* w_reg = (const float*)d_in[6];
    float* out = (float*)d_out;
    float* ws  = (float*)d_ws;

    hipLaunchKernelGGL(prep_weights, dim3((32 * 1152 + 255) / 256), dim3(256),
                       0, stream, w_off, w_mod, w_reg, ws);
    hipLaunchKernelGGL(conv_mfma, dim3(Ww / 16, Hh / 4, Bn), dim3(256),
                       0, stream, x, guide, ws, b_off, b_mod, ws + PAR_OFF);
    hipLaunchKernelGGL(deform_mfma, dim3(Ww / 16, Hh / 4, Bn), dim3(256),
                       0, stream, x, ws, ws + PAR_OFF, out);
}

// Round 4
// 153.467 us; speedup vs baseline: 1.5152x; 1.5089x over previous
//
#include <hip/hip_runtime.h>
#include <math.h>

// Problem constants
#define Bn   4
#define Cc   64
#define Hh   128
#define Ww   128
#define Oo   64
#define HW   16384
#define NPAR 27

// Workspace layout (float offsets)
#define WB2_OFF 0        // bf16 AT2[t][cc][mt2][lane64][8] = 36864 shorts
#define WB_OFF  18432    // bf16 ATd[t][h][mt4][lane64][8]  = 36864 shorts
#define PAR_OFF 36864    // f32 par[B][27][HW]

typedef __attribute__((ext_vector_type(8))) short bf16x8;
typedef __attribute__((ext_vector_type(4))) short s16x4;
typedef __attribute__((ext_vector_type(4))) float f32x4;
typedef __attribute__((ext_vector_type(2), aligned(4))) float f32x2u;

__device__ __forceinline__ short f2bf(float f) {
    unsigned u = __builtin_bit_cast(unsigned, f);
    u += 0x7FFFu + ((u >> 16) & 1u);        // RNE
    return (short)(u >> 16);
}

// ---------------------------------------------------------------------------
// prep: pre-transpose weights into MFMA A-fragment order so the main kernels
// read A with COALESCED dwordx4 (r0-r3 read lane-stride-2304B = 64-transaction
// divergent loads, 72x per wave). K is reordered tap-major (t*128+ch for conv,
// t*64+ch for deform); both kernels' B construction matches this order.
//   AT2[i]: i = t*4096 + cc*1024 + mt*512 + l*8 + j ; elem = W2[mt*16+(l&15)]
//           [ch=cc*32+(l>>4)*8+j, tap t] ; W2 rows 0-17 w_off, 18-26 w_mod, pad 0
//   ATd[e]: e = t*4096 + h*2048 + mt*512 + l*8 + j ; elem = w_reg[mt*16+(l&15)]
//           [ch=h*32+(l>>4)*8+j, tap t]
// ---------------------------------------------------------------------------
__global__ void prep_weights(const float* __restrict__ w_off,
                             const float* __restrict__ w_mod,
                             const float* __restrict__ w_reg,
                             float* __restrict__ ws) {
    int i = blockIdx.x * 256 + threadIdx.x;
    short* at2 = (short*)(ws + WB2_OFF);
    short* atd = (short*)(ws + WB_OFF);
    if (i < 36864) {
        int j = i & 7, l = (i >> 3) & 63, mt = (i >> 9) & 1, cc = (i >> 10) & 3, t = i >> 12;
        int lm = l & 15, quad = l >> 4;
        int row = mt * 16 + lm;
        int c = cc * 32 + quad * 8 + j;
        float v = 0.f;
        if (row < 18)      v = w_off[row * 1152 + c * 9 + t];
        else if (row < 27) v = w_mod[(row - 18) * 1152 + c * 9 + t];
        at2[i] = f2bf(v);
    } else if (i < 73728) {
        int e = i - 36864;
        int j = e & 7, l = (e >> 3) & 63, mt = (e >> 9) & 3, h = (e >> 11) & 1, t = e >> 12;
        int lm = l & 15, quad = l >> 4;
        int o = mt * 16 + lm;
        int c = h * 32 + quad * 8 + j;
        atd[e] = f2bf(w_reg[o * 576 + c * 9 + t]);
    }
}

// ---------------------------------------------------------------------------
// conv_mfma round 4: barrier-free direct conv. The r0-r3 "everything idle"
// signature (Mfma 2%, VALU 25%, HBM 8%) was the lockstep V-round-trip:
// gather -> ds_write -> barrier -> ds_read -> tiny MFMA, x36 barriers.
// Now: stage the 6x24 window for all 128 ch ONCE as bf16 channel-inner
// [pos][ch(+8 pad)] with zero-filled halo; each B-fragment is then ONE
// ds_read_b128 at a tap-shifted position (lane=pixel, 8 consecutive ch =
// 8 consecutive k). A-fragments are coalesced dwordx4 from AT2. K-loop:
// 36 ds_read + 72 A-loads + 72 MFMA, ZERO barriers. Window bf16 values =
// f2bf(x) exactly as the old V, so numerics are unchanged.
// ---------------------------------------------------------------------------
#define CPSTR 136   // bf16 elems per position: 128 ch + 8 pad (272B; 68 words -> banks step 4)

__global__ __launch_bounds__(256, 4)
void conv_mfma(const float* __restrict__ x, const float* __restrict__ g,
               const float* __restrict__ ws_,
               const float* __restrict__ b_off, const float* __restrict__ b_mod,
               float* __restrict__ parw) {
    __shared__ __align__(16) short Wd[144 * CPSTR];   // 39168 B -> 4 blocks/CU

    const int tid = threadIdx.x;
    const int l = tid & 63, lm = l & 15, quad = l >> 4;
    const int w = __builtin_amdgcn_readfirstlane(tid >> 6);   // wave = pixel row
    const int b = blockIdx.z;
    const int ho0 = blockIdx.y * 4, wo0 = blockIdx.x * 16;
    const int row_base = ho0 - 1;     // may be -1: halo rows zero-filled
    const int col_base = wo0 - 4;     // 4-aligned; halo cols zero-filled

    const short* at2 = (const short*)(ws_ + WB2_OFF);
    const float* xb = x + ((size_t)(b * Cc) << 14);
    const float* gb = g + ((size_t)(b * Cc) << 14);

    // Stage window: 36 pos-quads x 32 ch-quads; per task 4 coalesced f32x4
    // loads (4 ch, same 4 cols), 4x4 transpose, 4 ds_write_b64 ch-inner.
    for (int s = tid; s < 1152; s += 256) {
        int pq = s >> 5, cq = s & 31;
        int r = pq / 6, c4 = (pq - r * 6) * 4;
        int row = row_base + r, col = col_base + c4;
        bool ok = ((unsigned)row < 128u) && ((unsigned)col < 128u);  // col%4==0 -> group all-in/all-out
        f32x4 v0, v1, v2, v3;
        {
            int ch = cq * 4;
            const float* p0 = (ch < Cc) ? (xb + ((size_t)ch << 14)) : (gb + ((size_t)(ch - Cc) << 14));
            const float* p1 = (ch + 1 < Cc) ? (xb + ((size_t)(ch + 1) << 14)) : (gb + ((size_t)(ch + 1 - Cc) << 14));
            const float* p2 = (ch + 2 < Cc) ? (xb + ((size_t)(ch + 2) << 14)) : (gb + ((size_t)(ch + 2 - Cc) << 14));
            const float* p3 = (ch + 3 < Cc) ? (xb + ((size_t)(ch + 3) << 14)) : (gb + ((size_t)(ch + 3 - Cc) << 14));
            f32x4 zz = {0.f, 0.f, 0.f, 0.f};
            size_t off = ((size_t)(row << 7) + col);
            v0 = ok ? *(const f32x4*)(p0 + off) : zz;
            v1 = ok ? *(const f32x4*)(p1 + off) : zz;
            v2 = ok ? *(const f32x4*)(p2 + off) : zz;
            v3 = ok ? *(const f32x4*)(p3 + off) : zz;
        }
#pragma unroll
        for (int p = 0; p < 4; p++) {
            s16x4 o4 = { f2bf(v0[p]), f2bf(v1[p]), f2bf(v2[p]), f2bf(v3[p]) };
            *(s16x4*)&Wd[(r * 24 + c4 + p) * CPSTR + cq * 4] = o4;
        }
    }
    __syncthreads();   // the ONLY barrier

    f32x4 acc0 = {0.f, 0.f, 0.f, 0.f}, acc1 = {0.f, 0.f, 0.f, 0.f};
#pragma unroll
    for (int t = 0; t < 9; t++) {
        int dy = t / 3, dx = t - dy * 3;
        int pos = (w + dy) * 24 + (lm + dx + 3);    // in-window coords, no masks
#pragma unroll
        for (int cc = 0; cc < 4; cc++) {
            bf16x8 bfr = *(const bf16x8*)&Wd[pos * CPSTR + cc * 32 + quad * 8];
            bf16x8 a0 = *(const bf16x8*)(at2 + t * 4096 + cc * 1024 + l * 8);
            bf16x8 a1 = *(const bf16x8*)(at2 + t * 4096 + cc * 1024 + 512 + l * 8);
            acc0 = __builtin_amdgcn_mfma_f32_16x16x32_bf16(a0, bfr, acc0, 0, 0, 0);
            acc1 = __builtin_amdgcn_mfma_f32_16x16x32_bf16(a1, bfr, acc1, 0, 0, 0);
        }
    }

    // Epilogue: D[row j][col lm] -> par channels, fused bias/coords/sigmoid
    const int ho = ho0 + w, wo = wo0 + lm;
    const int pix = (ho << 7) + wo;
    float* par = parw + (size_t)b * NPAR * HW + pix;
#pragma unroll
    for (int mt = 0; mt < 2; mt++) {
        f32x4 a = mt ? acc1 : acc0;
#pragma unroll
        for (int reg = 0; reg < 4; reg++) {
            int j = mt * 16 + quad * 4 + reg;
            float v = a[reg];
            if (j < 18) {
                int k = j >> 1;
                float vb = v + b_off[j];
                if (j & 1) par[(size_t)(9 + k) * HW] = vb + (float)(k - (k / 3) * 3 + wo - 1);
                else       par[(size_t)k * HW]       = vb + (float)(k / 3 + ho - 1);
            } else if (j < 27) {
                int k = j - 18;
                par[(size_t)(18 + k) * HW] = 2.f / (1.f + __expf(-(v + b_mod[k])));
            }
        }
    }
}

// ---------------------------------------------------------------------------
// deform_mfma round 4: barrier-free K-loop. Waves own pixel-rows (not
// o-tiles); each lane builds its OWN B-fragment (8 consecutive ch at its
// pixel/tap) from a channel-inner f32 window [pos][ch32(+4 pad)] staged per
// c-half: 8 ds_read_b128 + 32 FMA per chunk, then 4 MFMA (all m-tiles).
// 4x gather redundancy across waves, but ZERO barriers in the K-loop
// (2 barrier pairs total for the half re-stage). Out-of-halo offsets ->
// block-uniform global-gather fallback (rare at sigma~0.35). f32 corners
// and folded weights identical to r3 -> numerics unchanged.
// ---------------------------------------------------------------------------
#define DPSTR 36   // f32 per position: 32 ch + 4 pad (144B; banks step 4)

__global__ __launch_bounds__(256, 3)
void deform_mfma(const float* __restrict__ x, const float* __restrict__ ws_,
                 const float* __restrict__ par_base, float* __restrict__ out) {
    __shared__ __align__(16) float Xw[240 * DPSTR];   // 34560 B
    __shared__ int2   sIdx[576];                      // image-coord pair bases
    __shared__ float4 sWt [576];
    __shared__ int sOk;

    const int tid = threadIdx.x;
    const int l = tid & 63, lm = l & 15, quad = l >> 4;
    const int w = __builtin_amdgcn_readfirstlane(tid >> 6);   // wave = pixel row
    const int b = blockIdx.z;

    const int ho0 = blockIdx.y * 4, wo0 = blockIdx.x * 16;
    const int rb = min(max(ho0 - 3, 0), 128 - 10);
    const int cb = min(max(wo0 - 4, 0), 128 - 24);    // 4-aligned

    const float* par = par_base + (size_t)b * NPAR * HW;
    const short* atd = (const short*)(ws_ + WB_OFF);
    const float* xb  = x + ((size_t)(b * Cc) << 14);

    if (tid == 0) sOk = 1;
    __syncthreads();

    // Stage A: bilinear params for 9 taps x 64 pixels + in-tile check
    int okAll = 1;
    for (int s = tid; s < 576; s += 256) {
        int k = s >> 6;
        int sl = s & 63;
        int sho = ho0 + (sl >> 4);
        int swo = wo0 + (sl & 15);
        int spix = (sho << 7) + swo;
        float py = par[(size_t)k * HW + spix];
        float px = par[(size_t)(9 + k) * HW + spix];
        float m  = par[(size_t)(18 + k) * HW + spix];
        float fy = floorf(py), fx = floorf(px);
        int y0 = (int)fy, x0 = (int)fx;
        int y1 = y0 + 1;
        float wy1 = py - fy, wx1 = px - fx;
        float wy0 = 1.f - wy1, wx0 = 1.f - wx1;
        bool vy0 = (unsigned)y0 < 128u, vy1 = (unsigned)y1 < 128u;
        bool vx0 = (unsigned)x0 < 128u, vx1 = (unsigned)(x0 + 1) < 128u;
        int cy0 = min(max(y0, 0), 127), cy1 = min(max(y1, 0), 127);
        int bx2 = min(max(x0, 0), 126);
        bool sel_lo = (x0 < 0), sel_hi = (x0 > 126);
        float w00 = (vy0 && vx0) ? wy0 * wx0 * m : 0.f;
        float w01 = (vy0 && vx1) ? wy0 * wx1 * m : 0.f;
        float w10 = (vy1 && vx0) ? wy1 * wx0 * m : 0.f;
        float w11 = (vy1 && vx1) ? wy1 * wx1 * m : 0.f;
        // fold boundary handling into pair weights: wa->[bx2], wb->[bx2+1]
        float wa0 = sel_lo ? w01 : (sel_hi ? 0.f : w00);
        float wb0 = sel_hi ? w00 : (sel_lo ? 0.f : w01);
        float wa1 = sel_lo ? w11 : (sel_hi ? 0.f : w10);
        float wb1 = sel_hi ? w10 : (sel_lo ? 0.f : w11);
        sIdx[s] = make_int2((cy0 << 7) + bx2, (cy1 << 7) + bx2);
        sWt[s]  = make_float4(wa0, wb0, wa1, wb1);
        bool in = ((unsigned)(cy0 - rb) <= 9u) &&
                  ((unsigned)(cy1 - rb) <= 9u) &&
                  ((unsigned)(bx2 - cb) <= 22u);
        if (!in) okAll = 0;
    }
    if (!okAll) sOk = 0;

    // window stage: 60 pos-quads x 8 ch-quads; 4 f32x4 loads + transpose +
    // 4 f32x4 ds_writes, ch-inner. All positions in-image (bases clamped).
    auto STAGE = [&](int h) {
        for (int s = tid; s < 480; s += 256) {
            int pq = s >> 3, cq = s & 7;
            int r = pq / 6, c4 = (pq - r * 6) * 4;
            size_t off = (size_t)((rb + r) << 7) + cb + c4;
            f32x4 v0 = *(const f32x4*)(xb + ((size_t)(h * 32 + cq * 4 + 0) << 14) + off);
            f32x4 v1 = *(const f32x4*)(xb + ((size_t)(h * 32 + cq * 4 + 1) << 14) + off);
            f32x4 v2 = *(const f32x4*)(xb + ((size_t)(h * 32 + cq * 4 + 2) << 14) + off);
            f32x4 v3 = *(const f32x4*)(xb + ((size_t)(h * 32 + cq * 4 + 3) << 14) + off);
#pragma unroll
            for (int p = 0; p < 4; p++) {
                f32x4 o4 = { v0[p], v1[p], v2[p], v3[p] };
                *(f32x4*)&Xw[(r * 24 + c4 + p) * DPSTR + cq * 4] = o4;
            }
        }
    };

    STAGE(0);
    __syncthreads();
    const int fast = sOk;                 // block-uniform

    f32x4 acc[4];
#pragma unroll
    for (int mt = 0; mt < 4; mt++) acc[mt] = (f32x4){0.f, 0.f, 0.f, 0.f};

    auto T_LOOP = [&](int h) {
#pragma unroll
        for (int t = 0; t < 9; t++) {
            int s = t * 64 + w * 16 + lm;
            int2   id = sIdx[s];
            float4 wv = sWt [s];
            int ia = ((id.x >> 7) - rb) * 24 + ((id.x & 127) - cb);
            int ib = ((id.y >> 7) - rb) * 24 + ((id.y & 127) - cb);
            const float* pa = &Xw[ia * DPSTR + quad * 8];
            const float* pb = &Xw[ib * DPSTR + quad * 8];
            union { short s8[8]; bf16x8 v; } u;
#pragma unroll
            for (int hf = 0; hf < 2; hf++) {
                f32x4 p00 = *(const f32x4*)(pa + hf * 4);
                f32x4 p01 = *(const f32x4*)(pa + DPSTR + hf * 4);
                f32x4 p10 = *(const f32x4*)(pb + hf * 4);
                f32x4 p11 = *(const f32x4*)(pb + DPSTR + hf * 4);
#pragma unroll
                for (int j = 0; j < 4; j++)
                    u.s8[hf * 4 + j] = f2bf(wv.x * p00[j] + wv.y * p01[j] +
                                            wv.z * p10[j] + wv.w * p11[j]);
            }
#pragma unroll
            for (int mt = 0; mt < 4; mt++) {
                bf16x8 a = *(const bf16x8*)(atd + t * 4096 + h * 2048 + mt * 512 + l * 8);
                acc[mt] = __builtin_amdgcn_mfma_f32_16x16x32_bf16(a, u.v, acc[mt], 0, 0, 0);
            }
        }
    };

    if (fast) {
        T_LOOP(0);
        __syncthreads();      // all waves done reading half 0
        STAGE(1);
        __syncthreads();
        T_LOOP(1);
    } else {
        // rare fallback: offsets beyond halo -> global bilinear gather
#pragma unroll 1
        for (int h = 0; h < 2; h++) {
#pragma unroll 1
            for (int t = 0; t < 9; t++) {
                int s = t * 64 + w * 16 + lm;
                int2   id = sIdx[s];
                float4 wv = sWt [s];
                union { short s8[8]; bf16x8 v; } u;
#pragma unroll
                for (int j = 0; j < 8; j++) {
                    int c = h * 32 + quad * 8 + j;
                    const float* xc = xb + ((size_t)c << 14);
                    f32x2u q0 = *(const f32x2u*)(xc + id.x);
                    f32x2u q1 = *(const f32x2u*)(xc + id.y);
                    u.s8[j] = f2bf(wv.x * q0.x + wv.y * q0.y + wv.z * q1.x + wv.w * q1.y);
                }
#pragma unroll
                for (int mt = 0; mt < 4; mt++) {
                    bf16x8 a = *(const bf16x8*)(atd + t * 4096 + h * 2048 + mt * 512 + l * 8);
                    acc[mt] = __builtin_amdgcn_mfma_f32_16x16x32_bf16(a, u.v, acc[mt], 0, 0, 0);
                }
            }
        }
    }

    // Epilogue: D[row=quad*4+reg][col=lm]; o = mt*16+row, pixel = (ho0+w, wo0+lm)
    const int wo = wo0 + lm, ho = ho0 + w;
#pragma unroll
    for (int mt = 0; mt < 4; mt++) {
        float* op = out + ((size_t)(b * Oo + mt * 16 + quad * 4) << 14) + (ho << 7) + wo;
#pragma unroll
        for (int reg = 0; reg < 4; reg++)
            op[(size_t)reg << 14] = acc[mt][reg];
    }
}

// ---------------------------------------------------------------------------
extern "C" void kernel_launch(void* const* d_in, const int* in_sizes, int n_in,
                              void* d_out, int out_size, void* d_ws, size_t ws_size,
                              hipStream_t stream) {
    const float* x     = (const float*)d_in[0];
    const float* guide = (const float*)d_in[1];
    const float* w_off = (const float*)d_in[2];
    const float* b_off = (const float*)d_in[3];
    const float* w_mod = (const float*)d_in[4];
    const float* b_mod = (const float*)d_in[5];
    const float* w_reg = (const float*)d_in[6];
    float* out = (float*)d_out;
    float* ws  = (float*)d_ws;

    hipLaunchKernelGGL(prep_weights, dim3((73728 + 255) / 256), dim3(256),
                       0, stream, w_off, w_mod, w_reg, ws);
    hipLaunchKernelGGL(conv_mfma, dim3(Ww / 16, Hh / 4, Bn), dim3(256),
                       0, stream, x, guide, ws, b_off, b_mod, ws + PAR_OFF);
    hipLaunchKernelGGL(deform_mfma, dim3(Ww / 16, Hh / 4, Bn), dim3(256),
                       0, stream, x, ws, ws + PAR_OFF, out);
}